// Round 9
// baseline (132.673 us; speedup 1.0000x reference)
//
#include <hip/hip_runtime.h>

#define NTAG 32
#define START 30
#define STOP 31
#define LOG2E 1.44269504088896340736f
#define LN2 0.69314718055994530942f

__device__ __forceinline__ float fexp2(float x) {
#if __has_builtin(__builtin_amdgcn_exp2f)
    return __builtin_amdgcn_exp2f(x);   // v_exp_f32: 2^x
#else
    return exp2f(x);
#endif
}
__device__ __forceinline__ float flog2(float x) {
#if __has_builtin(__builtin_amdgcn_logf)
    return __builtin_amdgcn_logf(x);    // v_log_f32: log2(x)
#else
    return log2f(x);
#endif
}

// Direction-agnostic half-exchange l <-> l+32 (VALU).  a==b==x on entry ->
// {a,b} = {own, partner} in SOME order -> a+b = own+partner.  R8-proven.
__device__ __forceinline__ void plswap32(float &a, float &b) {
#if __has_builtin(__builtin_amdgcn_permlane32_swap)
    auto r = __builtin_amdgcn_permlane32_swap(__float_as_int(a), __float_as_int(b),
                                              false, false);
    a = __int_as_float(r[0]);
    b = __int_as_float(r[1]);
#else
    asm volatile("s_nop 1\n\tv_permlane32_swap_b32 %0, %1" : "+v"(a), "+v"(b));
#endif
}
// Direction-agnostic 16-row exchange l <-> l^16 (VALU), same sum trick.
__device__ __forceinline__ void plswap16(float &a, float &b) {
#if __has_builtin(__builtin_amdgcn_permlane16_swap)
    auto r = __builtin_amdgcn_permlane16_swap(__float_as_int(a), __float_as_int(b),
                                              false, false);
    a = __int_as_float(r[0]);
    b = __int_as_float(r[1]);
#else
    asm volatile("s_nop 1\n\tv_permlane16_swap_b32 %0, %1" : "+v"(a), "+v"(b));
#endif
}

// DPP ROW_ROR control = 0x120 + r (rotate within 16-lane rows).  Applied to
// an int at init to DISCOVER the hw rotation map (R3-proven), so the E
// coefficients are correct regardless of ror direction semantics.
#define DPP_ROR_I(x, R) __builtin_amdgcn_update_dpp(0, (x), 0x120 + (R), 0xf, 0xf, false)

#define REPEAT15(M) \
    M(1) M(2) M(3) M(4) M(5) M(6) M(7) M(8) \
    M(9) M(10) M(11) M(12) M(13) M(14) M(15)

// rotation ops: DPP on src0 (the broadcast value y), plain VGPR E coefficient
#define MROT(r, A) asm volatile("v_mul_f32 %0, %1, %2 row_ror:" #r \
                                : "=v"(A) : "v"(y_), "v"(E_##r));
#define FROT(r, A) asm volatile("v_fmac_f32 %0, %1, %2 row_ror:" #r \
                                : "+v"(A) : "v"(y_), "v"(E_##r));

// One LINEAR-domain step, ALL-VALU (no DS on the chain):
//  - lane holds y for tag htag; 16 row-rotations (r=0 own + 15 DPP) gather its
//    row's 16-tag block; rows 0/2 (1/3) hold complementary blocks for outputs
//    0-15 (16-31) -> plswap32 pair-sum completes the 32-term dot.
//  - rows 2,3 then restore their held block via plswap16 sum minus own.
// PRE=0 fwd: S <- (M^T S)*F (F by otag);  PRE=1 bwd: S <- M(S*F) (F by htag).
// RN: wave-uniform exact pow2 renorm via readfirstlane (lane0 = tag 0, exact).
#define STEP_CORE(fraw_, PRE, RN) { \
    const float F_ = fexp2((fraw_) * LOG2E); \
    const float y_ = (PRE) ? (S * F_) : S; \
    float a0, a1, a2, a3; \
    a0 = y_ * E_0; \
    asm volatile("s_nop 1"); /* VALU-write -> DPP-read wait states */ \
    MROT(1, a1) MROT(2, a2) MROT(3, a3) \
    FROT(4, a0) FROT(5, a1) FROT(6, a2) FROT(7, a3) \
    FROT(8, a0) FROT(9, a1) FROT(10, a2) FROT(11, a3) \
    FROT(12, a0) FROT(13, a1) FROT(14, a2) FROT(15, a3) \
    const float part_ = (a0 + a1) + (a2 + a3); \
    float px_ = part_, py_ = part_; \
    plswap32(px_, py_); \
    const float tot_ = px_ + py_; \
    const float val_ = (PRE) ? tot_ : (tot_ * F_); \
    float tx_ = val_, ty_ = val_; \
    plswap16(tx_, ty_); \
    const float corr_ = (tx_ + ty_) - val_;   /* partner value, direction-proof */ \
    S = needX ? corr_ : val_; \
    if (RN) { \
        const int b0_ = __builtin_amdgcn_readfirstlane(__float_as_int(S)); \
        const int k_ = ((b0_ >> 23) & 0xff) - 127; \
        S = __int_as_float(__float_as_int(S) - (k_ << 23)); \
        M2i += k_; } }

// forward: consume FS, reload with time index tload (16 steps ahead, clamped up)
#define STEP_RELOAD_F(FS, tload, RN) { const float fraw_ = FS; \
    { const int tc_ = ((tload) < L - 1) ? (tload) : (L - 1); \
      FS = frow[tc_ * NTAG + fj]; } \
    STEP_CORE(fraw_, 0, RN) }
// backward: consume FS, reload with time index tload (16 steps behind, clamped at 0)
#define STEP_RELOAD_B(FS, tload, RN) { const float fraw_ = FS; \
    { const int tc_ = ((tload) > 0) ? (tload) : 0; \
      FS = frow[tc_ * NTAG + fj]; } \
    STEP_CORE(fraw_, 1, RN) }

#define STEP_NR_F(FS, RN) { const float fraw_ = FS; STEP_CORE(fraw_, 0, RN) }
#define STEP_NR_B(FS, RN) { const float fraw_ = FS; STEP_CORE(fraw_, 1, RN) }

// zero-instruction insurance against E remat/spill
#define PIN_E \
    asm volatile("" : "+v"(E_0),  "+v"(E_1),  "+v"(E_2),  "+v"(E_3), \
                      "+v"(E_4),  "+v"(E_5),  "+v"(E_6),  "+v"(E_7)); \
    asm volatile("" : "+v"(E_8),  "+v"(E_9),  "+v"(E_10), "+v"(E_11), \
                      "+v"(E_12), "+v"(E_13), "+v"(E_14), "+v"(E_15));

// Block = 768 threads = 12 waves, grid = B/4 = 256 blocks = 1 block/CU.
// Waves 0-3: FORWARD half-chains (batch blk*4+w), steps t=1..h-1, h=(n+1)/2.
// Waves 4-7: BACKWARD half-chains.  Waves 8-11: gold gathers.
// Chain steps are pure VALU (DPP rotations + permlane) -> per-step latency is
// issue+short dep tails, not the ~150-200cy LDS write->read RAW of R8.
__global__ __launch_bounds__(768, 1) void crf_nll_kernel(
    const float* __restrict__ feats,   // B x L x 32
    const float* __restrict__ trans,   // 32 x 32
    const int*   __restrict__ tags,    // B x L
    const int*   __restrict__ wsl,     // B
    float* __restrict__ out, int B, int L)
{
    __shared__ float strans[NTAG * NTAG];
    __shared__ float sRes[8][NTAG];    // fwd S (0-3), bwd x (4-7)
    __shared__ int   sM2[8];           // per-wave renorm exponent (uniform)
    for (int i = threadIdx.x; i < NTAG * NTAG; i += 768) strans[i] = trans[i];
    __syncthreads();

    const int wave = threadIdx.x >> 6;
    const int lane = threadIdx.x & 63;

    if (wave < 8) {
        const int dir = wave >> 2;            // 0 = fwd, 1 = bwd
        int b = blockIdx.x * 4 + (wave & 3);
        if (b >= B) b = B - 1;
        b = __builtin_amdgcn_readfirstlane(b);

        const int row  = lane >> 4;           // 16-lane row
        const int j16  = lane & 15;
        const int hrow = (row == 1 || row == 2) ? 1 : 0;
        const int htag = j16 + (hrow << 4);   // tag this lane HOLDS
        const int otag = j16 + ((row & 1) << 4); // tag this lane OUTPUTS
        const bool needX = (row >= 2);        // rows 2,3 take partner value

        const int n = __builtin_amdgcn_readfirstlane(wsl[b]);
        const int h = (n + 1) >> 1;           // meet point
        const float* __restrict__ frow = feats + (size_t)b * L * NTAG;
        float S;
        int M2i = 0;

        if (dir == 0) {
            // ========== forward: S(0) -> S(h-1), cnt = h-1 steps ============
            // E_r = e^trans[src_tag(r)][otag]; src via hw-discovered ror map
            float E_0 = fexp2(strans[htag * NTAG + otag] * LOG2E);
#define DECL_E(r) const int q##r = DPP_ROR_I(htag, r); \
                  float E_##r = fexp2(strans[q##r * NTAG + otag] * LOG2E);
            REPEAT15(DECL_E)
#undef DECL_E
            const int fj = otag;              // fwd: F multiplies OUTPUT tag
            S = fexp2((strans[START * NTAG + htag] + frow[htag]) * LOG2E);
#define LDF(t_) frow[(((t_) < L - 1) ? (t_) : (L - 1)) * NTAG + fj]
            float fA0 = LDF(1),  fA1 = LDF(2),  fA2 = LDF(3),  fA3 = LDF(4),
                  fA4 = LDF(5),  fA5 = LDF(6),  fA6 = LDF(7),  fA7 = LDF(8);
            float fB0 = LDF(9),  fB1 = LDF(10), fB2 = LDF(11), fB3 = LDF(12),
                  fB4 = LDF(13), fB5 = LDF(14), fB6 = LDF(15), fB7 = LDF(16);
#undef LDF
            int t = 1;
            for (; t + 16 <= h; t += 16) {
                PIN_E
                STEP_RELOAD_F(fA0, t + 16, 0)
                STEP_RELOAD_F(fA1, t + 17, 0)
                STEP_RELOAD_F(fA2, t + 18, 0)
                STEP_RELOAD_F(fA3, t + 19, 1)   // exact pow2 renorm /4
                STEP_RELOAD_F(fA4, t + 20, 0)
                STEP_RELOAD_F(fA5, t + 21, 0)
                STEP_RELOAD_F(fA6, t + 22, 0)
                STEP_RELOAD_F(fA7, t + 23, 1)
                STEP_RELOAD_F(fB0, t + 24, 0)
                STEP_RELOAD_F(fB1, t + 25, 0)
                STEP_RELOAD_F(fB2, t + 26, 0)
                STEP_RELOAD_F(fB3, t + 27, 1)
                STEP_RELOAD_F(fB4, t + 28, 0)
                STEP_RELOAD_F(fB5, t + 29, 0)
                STEP_RELOAD_F(fB6, t + 30, 0)
                STEP_RELOAD_F(fB7, t + 31, 1)
            }
            if (t + 0  < h) { STEP_NR_F(fA0, 1) }
            if (t + 1  < h) { STEP_NR_F(fA1, 1) }
            if (t + 2  < h) { STEP_NR_F(fA2, 1) }
            if (t + 3  < h) { STEP_NR_F(fA3, 1) }
            if (t + 4  < h) { STEP_NR_F(fA4, 1) }
            if (t + 5  < h) { STEP_NR_F(fA5, 1) }
            if (t + 6  < h) { STEP_NR_F(fA6, 1) }
            if (t + 7  < h) { STEP_NR_F(fA7, 1) }
            if (t + 8  < h) { STEP_NR_F(fB0, 1) }
            if (t + 9  < h) { STEP_NR_F(fB1, 1) }
            if (t + 10 < h) { STEP_NR_F(fB2, 1) }
            if (t + 11 < h) { STEP_NR_F(fB3, 1) }
            if (t + 12 < h) { STEP_NR_F(fB4, 1) }
            if (t + 13 < h) { STEP_NR_F(fB5, 1) }
            if (t + 14 < h) { STEP_NR_F(fB6, 1) }
        } else {
            // ========== backward: x = u, t = n-1 .. h, cnt = n-h ============
            // x_new[j] = sum_i (x_i * F_{t,i}) e^trans[j][i] -> E transposed
            float E_0 = fexp2(strans[otag * NTAG + htag] * LOG2E);
#define DECL_E(r) const int q##r = DPP_ROR_I(htag, r); \
                  float E_##r = fexp2(strans[otag * NTAG + q##r] * LOG2E);
            REPEAT15(DECL_E)
#undef DECL_E
            const int fj = htag;              // bwd: F multiplies HELD tag
            S = fexp2(strans[htag * NTAG + STOP] * LOG2E);   // u_htag
            const int cnt = n - h;
#define LDB(s_) frow[(((n - 1 - (s_)) > 0) ? (n - 1 - (s_)) : 0) * NTAG + fj]
            float gA0 = LDB(0),  gA1 = LDB(1),  gA2 = LDB(2),  gA3 = LDB(3),
                  gA4 = LDB(4),  gA5 = LDB(5),  gA6 = LDB(6),  gA7 = LDB(7);
            float gB0 = LDB(8),  gB1 = LDB(9),  gB2 = LDB(10), gB3 = LDB(11),
                  gB4 = LDB(12), gB5 = LDB(13), gB6 = LDB(14), gB7 = LDB(15);
#undef LDB
            int s = 0;
            for (; s + 16 <= cnt; s += 16) {
                PIN_E
                STEP_RELOAD_B(gA0, n - 1 - (s + 0)  - 16, 0)
                STEP_RELOAD_B(gA1, n - 1 - (s + 1)  - 16, 0)
                STEP_RELOAD_B(gA2, n - 1 - (s + 2)  - 16, 0)
                STEP_RELOAD_B(gA3, n - 1 - (s + 3)  - 16, 1)
                STEP_RELOAD_B(gA4, n - 1 - (s + 4)  - 16, 0)
                STEP_RELOAD_B(gA5, n - 1 - (s + 5)  - 16, 0)
                STEP_RELOAD_B(gA6, n - 1 - (s + 6)  - 16, 0)
                STEP_RELOAD_B(gA7, n - 1 - (s + 7)  - 16, 1)
                STEP_RELOAD_B(gB0, n - 1 - (s + 8)  - 16, 0)
                STEP_RELOAD_B(gB1, n - 1 - (s + 9)  - 16, 0)
                STEP_RELOAD_B(gB2, n - 1 - (s + 10) - 16, 0)
                STEP_RELOAD_B(gB3, n - 1 - (s + 11) - 16, 1)
                STEP_RELOAD_B(gB4, n - 1 - (s + 12) - 16, 0)
                STEP_RELOAD_B(gB5, n - 1 - (s + 13) - 16, 0)
                STEP_RELOAD_B(gB6, n - 1 - (s + 14) - 16, 0)
                STEP_RELOAD_B(gB7, n - 1 - (s + 15) - 16, 1)
            }
            if (s + 0  < cnt) { STEP_NR_B(gA0, 1) }
            if (s + 1  < cnt) { STEP_NR_B(gA1, 1) }
            if (s + 2  < cnt) { STEP_NR_B(gA2, 1) }
            if (s + 3  < cnt) { STEP_NR_B(gA3, 1) }
            if (s + 4  < cnt) { STEP_NR_B(gA4, 1) }
            if (s + 5  < cnt) { STEP_NR_B(gA5, 1) }
            if (s + 6  < cnt) { STEP_NR_B(gA6, 1) }
            if (s + 7  < cnt) { STEP_NR_B(gA7, 1) }
            if (s + 8  < cnt) { STEP_NR_B(gB0, 1) }
            if (s + 9  < cnt) { STEP_NR_B(gB1, 1) }
            if (s + 10 < cnt) { STEP_NR_B(gB2, 1) }
            if (s + 11 < cnt) { STEP_NR_B(gB3, 1) }
            if (s + 12 < cnt) { STEP_NR_B(gB4, 1) }
            if (s + 13 < cnt) { STEP_NR_B(gB5, 1) }
            if (s + 14 < cnt) { STEP_NR_B(gB6, 1) }
        }
        // lanes 0-31: otag == htag == lane -> exact values, store directly
        if (lane < 32) {
            sRes[wave][lane] = S;
            if (lane == 0) sM2[wave] = M2i;
        }
    } else {
        // ================= gold waves (pure gathers) ========================
        int b = blockIdx.x * 4 + (wave - 8);
        if (b < B) {
            b = __builtin_amdgcn_readfirstlane(b);
            const int n = wsl[b];
            const float* __restrict__ frow = feats + (size_t)b * L * NTAG;
            const int*   __restrict__ trow = tags  + (size_t)b * L;
            float acc = 0.f;
            for (int tt = lane; tt < L; tt += 64) {
                const int tg = trow[tt];
                if (tt == 0) {
                    acc += strans[START * NTAG + tg] + frow[tg];
                } else if (tt < n) {
                    const int tgp = trow[tt - 1];
                    acc += strans[tgp * NTAG + tg] + frow[tt * NTAG + tg];
                }
                if (tt == n - 1) {
                    acc += strans[tg * NTAG + STOP];
                }
            }
#pragma unroll
            for (int k = 1; k < 64; k <<= 1) acc += __shfl_xor(acc, k, 64);
            if (lane == 0) atomicAdd(out, -acc);
        }
    }

    __syncthreads();

    // ============== combine: forward score = ln2*(M2f+M2b+log2(x . S)) ======
    if (wave < 4) {
        const int b2 = blockIdx.x * 4 + wave;
        if (b2 < B && lane < 32) {
            float ex = sRes[wave][lane] * sRes[wave + 4][lane];
#pragma unroll
            for (int k = 1; k < 32; k <<= 1) ex += __shfl_xor(ex, k, 32);
            if (lane == 0)
                atomicAdd(out, LN2 * ((float)(sM2[wave] + sM2[wave + 4]) + flog2(ex)));
        }
    }
}

extern "C" void kernel_launch(void* const* d_in, const int* in_sizes, int n_in,
                              void* d_out, int out_size, void* d_ws, size_t ws_size,
                              hipStream_t stream) {
    const float* feats = (const float*)d_in[0];
    const float* trans = (const float*)d_in[1];
    const int*   tags  = (const int*)d_in[2];
    const int*   wsl   = (const int*)d_in[3];
    float* out = (float*)d_out;

    const int B = in_sizes[3];              // word_seq_lens: (B,)
    const int L = in_sizes[2] / B;          // tags: (B, L)

    (void)hipMemsetAsync(out, 0, sizeof(float), stream);
    const int grid = (B + 3) / 4;
    crf_nll_kernel<<<grid, 768, 0, stream>>>(feats, trans, tags, wsl, out, B, L);
}